// Round 12
// baseline (151.884 us; speedup 1.0000x reference)
//
#include <hip/hip_runtime.h>
#include <math.h>

#define N_POSE   1024
#define M_TRAIN  10000
#define NJOINT   21
#define KNEIGH   5
#define CLIPV    (1.0f - 1e-7f)
#define HPI_F    1.57079632679490f
#define BIGF     1e30f
#define TPB      256
#define QN_FLOATS (N_POSE * NJOINT * 4)  // normalized-pose staging in ws

// one-shot: normalize all query quats so the hot loop has no rsqrt
__global__ __launch_bounds__(256)
void pose_norm_kernel(const float* __restrict__ pose, float* __restrict__ qn) {
    int i = blockIdx.x * blockDim.x + threadIdx.x;
    if (i >= N_POSE * NJOINT) return;
    float4 v = ((const float4*)pose)[i];
    float inv = rsqrtf(v.x * v.x + v.y * v.y + v.z * v.z + v.w * v.w);
    v.x *= inv; v.y *= inv; v.z *= inv; v.w *= inv;
    ((float4*)qn)[i] = v;
}

// Lane pair (r, r+32) shares one query row: half h=0 owns j0..j10 (11 real),
// h=1 owns j11..j20 (10 real + 1 masked dummy slot). Per-thread q = 44 floats
// -> resident at the allocator's ~64-VGPR budget BY CONSTRUCTION (R8 proved
// fit; R8's regression was per-load address VALU, removed here).
// Train loads: uniform base pointer (SGPR pair) + ONE per-lane byte-offset
// VGPR (voff/off10, prologue-computed) + compile-time immediates -> per-lane
// VMEM broadcast via L1, vmcnt-pipelined, zero per-load address math, and no
// scalar-path lgkm drains / K$ thrash (R10's stall mechanism).
__global__ __launch_bounds__(TPB)
void pose_dist_kernel(const float* __restrict__ qn,
                      const float* __restrict__ train,
                      float* __restrict__ topk,
                      int chunks, int mchunk) {
    const int nb   = blockIdx.x / chunks;   // row-group (0..7)
    const int cb   = blockIdx.x % chunks;   // m-chunk
    const int tid  = threadIdx.x;
    const int lane = tid & 63;
    const int h    = lane >> 5;                       // pair half
    const int n    = nb * 128 + (tid >> 6) * 32 + (lane & 31);

    const int voff  = h * 176;                        // byte offset of half's j-base
    const int off10 = voff + (h ? 144 : 160);         // 11th slot: h0->j10, h1->j20(dummy)
    const float mask10 = h ? 0.f : 1.f;

    float4 q[11];
    const char* qb = (const char*)qn + (size_t)n * 336;
#pragma unroll
    for (int jj = 0; jj < 10; ++jj) q[jj] = *(const float4*)(qb + voff + jj * 16);
    q[10] = *(const float4*)(qb + off10);
#pragma unroll
    for (int jj = 0; jj < 11; ++jj)
        asm volatile("" : "+v"(q[jj].x), "+v"(q[jj].y), "+v"(q[jj].z), "+v"(q[jj].w));

    float t0 = BIGF, t1 = BIGF, t2 = BIGF, t3 = BIGF, t4 = BIGF;
    const char* tb = (const char*)train + (size_t)cb * mchunk * 336;

#pragma unroll 1
    for (int mi = 0; mi < mchunk; ++mi) {
        const char* tm = tb + (size_t)mi * 336;       // uniform -> SGPR base
        float a0 = 0.f, a1 = 0.f;
#pragma unroll
        for (int jj = 0; jj < 11; ++jj) {
            float4 u = (jj < 10) ? *(const float4*)(tm + voff + jj * 16)
                                 : *(const float4*)(tm + off10);
            float4 p = q[jj];
            float d = u.x * p.x + u.y * p.y + u.z * p.z + u.w * p.w;
            float a = fminf(fabsf(d), CLIPV);
            float pl = fmaf(a, -0.0187293f, 0.0742610f);
            pl = fmaf(a, pl, -0.2121144f);
            pl = fmaf(a, pl, 1.5707288f);
            float r  = __builtin_amdgcn_sqrtf(1.0f - a) * pl;
            float cs = __builtin_copysignf(HPI_F - r, d);
            if (jj == 10) cs *= mask10;               // kill dummy (h=1 only)
            if (jj & 1) a1 += cs; else a0 += cs;
        }
        float S = a0 + a1;
        S += __shfl_xor(S, 32);                       // pair sum: full 21-joint total
        float v = (NJOINT * HPI_F - S) * 0.5f;
        t4 = fminf(t4, fmaxf(t3, v));
        t3 = fminf(t3, fmaxf(t2, v));
        t2 = fminf(t2, fmaxf(t1, v));
        t1 = fminf(t1, fmaxf(t0, v));
        t0 = fminf(t0, v);
    }

    if (lane < 32) {                                  // one writer per row
        float* w = topk + ((size_t)cb * N_POSE + n) * KNEIGH;
        w[0] = t0; w[1] = t1; w[2] = t2; w[3] = t3; w[4] = t4;
    }
}

// one wave per query row: merge chunks*5 candidates -> mean of top-5
__global__ __launch_bounds__(64)
void pose_reduce_kernel(const float* __restrict__ topk, float* __restrict__ out,
                        int chunks) {
    const int n = blockIdx.x;
    const int lane = threadIdx.x;
    const int total = chunks * KNEIGH;

    float t0 = BIGF, t1 = BIGF, t2 = BIGF, t3 = BIGF, t4 = BIGF;
    for (int i = lane; i < total; i += 64) {
        int cb = i / KNEIGH, k = i % KNEIGH;
        float v = topk[((size_t)cb * N_POSE + n) * KNEIGH + k];
        t4 = fminf(t4, fmaxf(t3, v));
        t3 = fminf(t3, fmaxf(t2, v));
        t2 = fminf(t2, fmaxf(t1, v));
        t1 = fminf(t1, fmaxf(t0, v));
        t0 = fminf(t0, v);
    }

    float sum = 0.f;
#pragma unroll
    for (int r = 0; r < KNEIGH; ++r) {
        float v = t0; int who = lane;
        for (int off = 32; off; off >>= 1) {
            float ov = __shfl_xor(v, off);
            int   ow = __shfl_xor(who, off);
            if (ov < v || (ov == v && ow < who)) { v = ov; who = ow; }
        }
        sum += v;
        if (lane == who) { t0 = t1; t1 = t2; t2 = t3; t3 = t4; t4 = BIGF; }
    }
    if (lane == 0) out[n] = sum * (1.0f / KNEIGH);
}

extern "C" void kernel_launch(void* const* d_in, const int* in_sizes, int n_in,
                              void* d_out, int out_size, void* d_ws, size_t ws_size,
                              hipStream_t stream) {
    const float* pose  = (const float*)d_in[0];
    const float* train = (const float*)d_in[1];
    float* out  = (float*)d_out;
    float* qn   = (float*)d_ws;                 // QN_FLOATS floats
    float* topk = (float*)d_ws + QN_FLOATS;

    // chunks=500 fits ws (proven R10). Tiers all divide 10000.
    size_t base = (size_t)QN_FLOATS * sizeof(float);
    int chunks = 500;
    if (base + (size_t)N_POSE * chunks * KNEIGH * sizeof(float) > ws_size) chunks = 250;
    if (base + (size_t)N_POSE * chunks * KNEIGH * sizeof(float) > ws_size) chunks = 125;
    if (base + (size_t)N_POSE * chunks * KNEIGH * sizeof(float) > ws_size) chunks = 50;
    if (base + (size_t)N_POSE * chunks * KNEIGH * sizeof(float) > ws_size) chunks = 10;
    const int mchunk = M_TRAIN / chunks;

    pose_norm_kernel<<<dim3((N_POSE * NJOINT + 255) / 256), dim3(256), 0, stream>>>(pose, qn);

    dim3 grid1((N_POSE / 128) * chunks);   // 8 row-groups x 500 chunks = 4000 blocks
    pose_dist_kernel<<<grid1, dim3(TPB), 0, stream>>>(qn, train, topk, chunks, mchunk);

    pose_reduce_kernel<<<dim3(N_POSE), dim3(64), 0, stream>>>(topk, out, chunks);
}